// Round 1
// baseline (170.663 us; speedup 1.0000x reference)
//
#include <hip/hip_runtime.h>

#define NXg 4096
#define NYg 4096
#define NELEM (NXg * NYg)

// CX = Z*DT/DX, CY = Z*DT/DY computed in double then rounded to f32,
// matching JAX's weak-scalar * float32-array promotion.
static constexpr double DTd = 1.0 / 400.0;
static constexpr double DXd = 1.0 / 4095.0;
static constexpr float CX = (float)(DTd / DXd);  // 10.2375
static constexpr float CY = (float)(DTd / DXd);  // DX == DY

// ---------------------------------------------------------------------------
// Kernel 1: final E field (both Ampere steps fused; boundary ring = X1).
// E1 (2-tap BC stencil) on [1,NX-2]^2; interior [2,NX-3]^2 adds the 4-tap f4
// stencil on ORIGINAL X2/X3. f4 = [(w-1)/3, -w, w, (1-w)/3].
// ---------------------------------------------------------------------------
__global__ __launch_bounds__(256) void e_kernel(
    const float* __restrict__ X1, const float* __restrict__ X2,
    const float* __restrict__ X3, const float* __restrict__ w1,
    float* __restrict__ E)
{
    int idx = blockIdx.x * 256 + threadIdx.x;
    if (idx >= NELEM) return;
    int i = idx >> 12;        // row
    int j = idx & (NYg - 1);  // col

    float x1 = X1[idx];
    float e;
    if (i == 0 || i == NXg - 1 || j == 0 || j == NYg - 1) {
        e = x1;  // untouched boundary
    } else {
        // step-1 Ampere (BC = [-1, 1], s = 1)
        float e1 = x1 + CX * (X3[idx] - X3[idx - NYg])
                      - CY * (X2[idx] - X2[idx - 1]);
        e = e1;
        if (i >= 2 && i <= NXg - 3 && j >= 2 && j <= NYg - 3) {
            float w  = w1[0];
            float f0 = (w - 1.0f) / 3.0f;
            float f1 = -w;
            float f2 = w;
            float f3 = (1.0f - w) / 3.0f;
            // step-2 Ampere (f4, s = 2) on ORIGINAL X3 (axis 0) / X2 (axis 1)
            float s1 = f0 * X3[idx - 2 * NYg] + f1 * X3[idx - NYg]
                     + f2 * X3[idx]           + f3 * X3[idx + NYg];
            float s2 = f0 * X2[idx - 2] + f1 * X2[idx - 1]
                     + f2 * X2[idx]     + f3 * X2[idx + 1];
            e = e1 + CX * s1 - CY * s2;
        }
    }
    E[idx] = e;
}

// ---------------------------------------------------------------------------
// Kernel 2: Hx, Hy. Step-3 Faraday (BC stencil on ORIGINAL X1), then step-4
// Faraday (f4 stencil on the FINAL E) applied on top in the interior.
// ---------------------------------------------------------------------------
__global__ __launch_bounds__(256) void h_kernel(
    const float* __restrict__ X1, const float* __restrict__ X2,
    const float* __restrict__ X3, const float* __restrict__ w1,
    const float* __restrict__ E,
    float* __restrict__ Hx, float* __restrict__ Hy)
{
    int idx = blockIdx.x * 256 + threadIdx.x;
    if (idx >= NELEM) return;
    int i = idx >> 12;
    int j = idx & (NYg - 1);

    float w  = w1[0];
    float f0 = (w - 1.0f) / 3.0f;
    float f1 = -w;
    float f2 = w;
    float f3 = (1.0f - w) / 3.0f;

    float x1 = X1[idx];

    // ---- Hx ----
    float hx = X2[idx];
    if (i >= 1 && i <= NXg - 2 && j <= NYg - 2) {
        // Hx1 = X2 - CY*(X1[i,j+1] - X1[i,j])
        hx = hx - CY * (X1[idx + 1] - x1);
    }
    if (i >= 2 && i <= NXg - 3 && j >= 1 && j <= NYg - 3) {
        // Hx2 = Hx1 - CY * sum_k f4[k] * E[i, j-1+k]
        float s3 = f0 * E[idx - 1] + f1 * E[idx]
                 + f2 * E[idx + 1] + f3 * E[idx + 2];
        hx = hx - CY * s3;
    }
    Hx[idx] = hx;

    // ---- Hy ----
    float hy = X3[idx];
    if (i <= NXg - 2 && j >= 1 && j <= NYg - 2) {
        // Hy1 = X3 + CX*(X1[i+1,j] - X1[i,j])
        hy = hy + CX * (X1[idx + NYg] - x1);
    }
    if (i >= 1 && i <= NXg - 3 && j >= 2 && j <= NYg - 3) {
        // Hy2 = Hy1 + CX * sum_k f4[k] * E[i-1+k, j]
        float s4 = f0 * E[idx - NYg] + f1 * E[idx]
                 + f2 * E[idx + NYg] + f3 * E[idx + 2 * NYg];
        hy = hy + CX * s4;
    }
    Hy[idx] = hy;
}

extern "C" void kernel_launch(void* const* d_in, const int* in_sizes, int n_in,
                              void* d_out, int out_size, void* d_ws, size_t ws_size,
                              hipStream_t stream) {
    const float* X1 = (const float*)d_in[0];
    const float* X2 = (const float*)d_in[1];
    const float* X3 = (const float*)d_in[2];
    const float* w1 = (const float*)d_in[3];

    float* E  = (float*)d_out;               // output 0
    float* Hx = (float*)d_out + NELEM;       // output 1
    float* Hy = (float*)d_out + 2 * NELEM;   // output 2

    dim3 block(256);
    dim3 grid(NELEM / 256);
    e_kernel<<<grid, block, 0, stream>>>(X1, X2, X3, w1, E);
    h_kernel<<<grid, block, 0, stream>>>(X1, X2, X3, w1, E, Hx, Hy);
}